// Round 2
// baseline (587.191 us; speedup 1.0000x reference)
//
#include <hip/hip_runtime.h>
#include <cmath>

#define B_      32
#define N_      4096
#define D_      512
#define D4      (D_/4)        // 128 float4 per row
#define NCH     64            // chunks per batch
#define RPC     64            // rows per chunk  (NCH*RPC == N_)
#define IN_DIM  1541          // 3*D + 5
#define NEG_SENT (-1.0e8f)
#define BIGNEG   (1.0e30f)

// ---------------- Kernel 1: per-(batch,chunk) partial sum/sumsq/max ----------
// Unconditional streaming: weight w in {0,1} from mask, no compaction, no
// load-address dependency on LDS values. 8 loads in flight per thread.
__global__ __launch_bounds__(128, 4) void stats_partial_kernel(
    const float* __restrict__ x, const float* __restrict__ mask,
    float4* __restrict__ psum, float4* __restrict__ psq,
    float4* __restrict__ pmax, float* __restrict__ pcnt)
{
    __shared__ float sw[RPC];   // 0 or 1
    __shared__ float so[RPC];   // 0 (valid) or -1e30 (invalid): (w-1)*1e30
    const int tx = threadIdx.x;    // 0..127, owns float4 lane tx
    const int c  = blockIdx.x;     // chunk
    const int b  = blockIdx.y;     // batch

    if (tx < RPC) {
        const float mv = mask[b * N_ + c * RPC + tx];
        const float w  = (mv > NEG_SENT) ? 1.f : 0.f;
        sw[tx] = w;
        so[tx] = (w - 1.f) * BIGNEG;
    }
    __syncthreads();

    const float4* __restrict__ xb =
        (const float4*)x + ((size_t)b * N_ + (size_t)c * RPC) * D4 + tx;

    float4 s0 = {0,0,0,0}, s1 = s0, s2 = s0, s3 = s0;
    float4 q0 = s0, q1 = s0, q2 = s0, q3 = s0;
    float4 m0 = {-BIGNEG,-BIGNEG,-BIGNEG,-BIGNEG}, m1 = m0, m2 = m0, m3 = m0;

    // S += w*V ; Q += (w*V)*V ; M = max(M, w*V + (w-1)*1e30)
#define ACC(S,Q,M,V,W,O) { \
    float tvx = (V).x*(W), tvy = (V).y*(W), tvz = (V).z*(W), tvw = (V).w*(W); \
    (S).x += tvx; (S).y += tvy; (S).z += tvz; (S).w += tvw; \
    (Q).x = fmaf(tvx,(V).x,(Q).x); (Q).y = fmaf(tvy,(V).y,(Q).y); \
    (Q).z = fmaf(tvz,(V).z,(Q).z); (Q).w = fmaf(tvw,(V).w,(Q).w); \
    (M).x = fmaxf((M).x, fmaf((W),(V).x,(O))); \
    (M).y = fmaxf((M).y, fmaf((W),(V).y,(O))); \
    (M).z = fmaxf((M).z, fmaf((W),(V).z,(O))); \
    (M).w = fmaxf((M).w, fmaf((W),(V).w,(O))); }

    #pragma unroll
    for (int j = 0; j < RPC; j += 8) {
        float4 v0 = xb[(size_t)(j+0) * D4];
        float4 v1 = xb[(size_t)(j+1) * D4];
        float4 v2 = xb[(size_t)(j+2) * D4];
        float4 v3 = xb[(size_t)(j+3) * D4];
        float4 v4 = xb[(size_t)(j+4) * D4];
        float4 v5 = xb[(size_t)(j+5) * D4];
        float4 v6 = xb[(size_t)(j+6) * D4];
        float4 v7 = xb[(size_t)(j+7) * D4];
        ACC(s0,q0,m0,v0, sw[j+0], so[j+0]);
        ACC(s1,q1,m1,v1, sw[j+1], so[j+1]);
        ACC(s2,q2,m2,v2, sw[j+2], so[j+2]);
        ACC(s3,q3,m3,v3, sw[j+3], so[j+3]);
        ACC(s0,q0,m0,v4, sw[j+4], so[j+4]);
        ACC(s1,q1,m1,v5, sw[j+5], so[j+5]);
        ACC(s2,q2,m2,v6, sw[j+6], so[j+6]);
        ACC(s3,q3,m3,v7, sw[j+7], so[j+7]);
    }
#undef ACC

    s0.x += s1.x+s2.x+s3.x; s0.y += s1.y+s2.y+s3.y;
    s0.z += s1.z+s2.z+s3.z; s0.w += s1.w+s2.w+s3.w;
    q0.x += q1.x+q2.x+q3.x; q0.y += q1.y+q2.y+q3.y;
    q0.z += q1.z+q2.z+q3.z; q0.w += q1.w+q2.w+q3.w;
    m0.x = fmaxf(fmaxf(m0.x,m1.x), fmaxf(m2.x,m3.x));
    m0.y = fmaxf(fmaxf(m0.y,m1.y), fmaxf(m2.y,m3.y));
    m0.z = fmaxf(fmaxf(m0.z,m1.z), fmaxf(m2.z,m3.z));
    m0.w = fmaxf(fmaxf(m0.w,m1.w), fmaxf(m2.w,m3.w));

    const size_t idx = ((size_t)(b * NCH + c)) * D4 + tx;
    psum[idx] = s0; psq[idx] = q0; pmax[idx] = m0;

    if (tx == 0) {  // count = sum of weights
        float cv = 0.f;
        #pragma unroll
        for (int j = 0; j < RPC; ++j) cv += sw[j];
        pcnt[b * NCH + c] = cv;
    }
}

// ---------------- Kernel 2: combine partials, build g, run MLP --------------
__global__ __launch_bounds__(256) void mlp_kernel(
    const float4* __restrict__ psum, const float4* __restrict__ psq,
    const float4* __restrict__ pmax, const float* __restrict__ pcnt,
    const float* __restrict__ W1, const float* __restrict__ b1,
    const float* __restrict__ W2, const float* __restrict__ b2,
    const float* __restrict__ W3, const float* __restrict__ b3,
    float* __restrict__ scores)
{
    __shared__ float4 Ss[2][D4], Sq[2][D4], Sm[2][D4];
    __shared__ float g[IN_DIM];
    __shared__ float h1p[4*64];
    __shared__ float h1[64];
    __shared__ float h2[32];
    __shared__ float scnt;

    const int tid = threadIdx.x;     // 0..255
    const int tx  = tid & 127;       // float4 lane
    const int ty  = tid >> 7;        // 0/1: which half of the chunks
    const int b   = blockIdx.x;

    {   // 2-way parallel chunk reduction
        float4 s = {0,0,0,0}, q = {0,0,0,0};
        float4 mx = {-BIGNEG,-BIGNEG,-BIGNEG,-BIGNEG};
        const int c0 = ty * (NCH/2);
        for (int c = c0; c < c0 + NCH/2; ++c) {
            const size_t idx = ((size_t)(b * NCH + c)) * D4 + tx;
            float4 a = psum[idx], u = psq[idx], w = pmax[idx];
            s.x += a.x; s.y += a.y; s.z += a.z; s.w += a.w;
            q.x += u.x; q.y += u.y; q.z += u.z; q.w += u.w;
            mx.x = fmaxf(mx.x,w.x); mx.y = fmaxf(mx.y,w.y);
            mx.z = fmaxf(mx.z,w.z); mx.w = fmaxf(mx.w,w.w);
        }
        Ss[ty][tx] = s; Sq[ty][tx] = q; Sm[ty][tx] = mx;
    }
    if (tid < 64) {   // count reduction over 64 chunks, first wave
        float cv = pcnt[b * NCH + tid];
        #pragma unroll
        for (int off = 32; off > 0; off >>= 1) cv += __shfl_down(cv, off);
        if (tid == 0) scnt = cv;
    }
    __syncthreads();

    const float cnt = scnt;
    if (ty == 0) {   // merge halves, compute g
        float4 s = Ss[0][tx], s_ = Ss[1][tx];
        float4 q = Sq[0][tx], q_ = Sq[1][tx];
        float4 mx = Sm[0][tx], m_ = Sm[1][tx];
        s.x += s_.x; s.y += s_.y; s.z += s_.z; s.w += s_.w;
        q.x += q_.x; q.y += q_.y; q.z += q_.z; q.w += q_.w;
        mx.x = fmaxf(mx.x,m_.x); mx.y = fmaxf(mx.y,m_.y);
        mx.z = fmaxf(mx.z,m_.z); mx.w = fmaxf(mx.w,m_.w);

        const bool  has = cnt > 0.f;
        const float inv = 1.f / fmaxf(cnt, 1.f);
        const float dn  = 1.f / fmaxf(cnt - 1.f, 1.f);
        float sa[4] = {s.x,s.y,s.z,s.w};
        float qa[4] = {q.x,q.y,q.z,q.w};
        float ma[4] = {mx.x,mx.y,mx.z,mx.w};
        #pragma unroll
        for (int k = 0; k < 4; ++k) {
            const int d = 4*tx + k;
            const float mn = has ? sa[k] * inv : 0.f;
            const float vv = fmaxf((qa[k] - cnt * mn * mn) * dn, 0.f);
            g[d]        = mn;
            g[D_ + d]   = has ? ma[k] : 0.f;
            g[2*D_ + d] = has ? sqrtf(vv) : 0.f;
        }
        if (tx == 0) {
            g[3*D_ + 0] = logf(cnt + 1.f) * 0.2f;
            g[3*D_ + 1] = 0.1f;
            g[3*D_ + 2] = 0.2f;
            g[3*D_ + 3] = 4.0f;
            g[3*D_ + 4] = 0.1f;
        }
    }
    __syncthreads();

    {   // layer 1: 1541 -> 64, 4-way split over input dim
        const int o   = tid & 63;
        const int grp = tid >> 6;    // 0..3
        float a = 0.f;
        for (int i = grp; i < IN_DIM; i += 4)
            a = fmaf(g[i], W1[i*64 + o], a);
        h1p[tid] = a;
    }
    __syncthreads();
    if (tid < 64) {
        float a = b1[tid] + ((h1p[tid] + h1p[64+tid]) + (h1p[128+tid] + h1p[192+tid]));
        h1[tid] = fmaxf(a, 0.f);
    }
    __syncthreads();

    if (tid < 32) {   // layer 2: 64 -> 32
        float a = b2[tid];
        #pragma unroll
        for (int i = 0; i < 64; ++i) a = fmaf(h1[i], W2[i*32 + tid], a);
        h2[tid] = fmaxf(a, 0.f);
    }
    __syncthreads();

    if (tid == 0) {   // layer 3: 32 -> 1, sigmoid
        float a = b3[0];
        #pragma unroll
        for (int i = 0; i < 32; ++i) a = fmaf(h2[i], W3[i], a);
        scores[b] = 1.f / (1.f + expf(-a));
    }
}

// ---------------- Kernel 3: reduce scores -> (num_clusters, score_mean) -----
__global__ __launch_bounds__(64) void final_kernel(
    const float* __restrict__ scores, float* __restrict__ out)
{
    const int t = threadIdx.x;
    float sc = (t < B_) ? scores[t] : 0.f;
    float r  = (t < B_) ? rintf(3.f + sc * 47.f) : 0.f;  // rintf == round-half-even == jnp.round
    #pragma unroll
    for (int off = 32; off > 0; off >>= 1) {
        sc += __shfl_down(sc, off);
        r  += __shfl_down(r,  off);
    }
    if (t == 0) {
        const float mean_r = r * (1.f / 32.f);   // exact: sum of ints / 2^5
        int nc = (int)mean_r;                    // astype(int32): truncate toward zero
        nc = nc < 3 ? 3 : (nc > 50 ? 50 : nc);
        out[0] = (float)nc;
        out[1] = sc * (1.f / 32.f);
    }
}

extern "C" void kernel_launch(void* const* d_in, const int* in_sizes, int n_in,
                              void* d_out, int out_size, void* d_ws, size_t ws_size,
                              hipStream_t stream)
{
    const float* x    = (const float*)d_in[0];
    const float* mask = (const float*)d_in[1];
    const float* W1   = (const float*)d_in[2];
    const float* b1   = (const float*)d_in[3];
    const float* W2   = (const float*)d_in[4];
    const float* b2   = (const float*)d_in[5];
    const float* W3   = (const float*)d_in[6];
    const float* b3   = (const float*)d_in[7];
    float* out = (float*)d_out;

    // workspace: psum | psq | pmax (each B*NCH*D4 float4 = 4 MB) | pcnt | scores
    const size_t PCOUNT = (size_t)B_ * NCH * D4;      // 262144 float4 per array
    float4* psum = (float4*)d_ws;
    float4* psq  = psum + PCOUNT;
    float4* pmax = psq  + PCOUNT;
    float*  pcnt = (float*)(pmax + PCOUNT);           // B_*NCH floats
    float*  scores = pcnt + (size_t)B_ * NCH;         // B_ floats

    dim3 gridA(NCH, B_);
    stats_partial_kernel<<<gridA, 128, 0, stream>>>(x, mask, psum, psq, pmax, pcnt);
    mlp_kernel<<<B_, 256, 0, stream>>>(psum, psq, pmax, pcnt,
                                       W1, b1, W2, b2, W3, b3, scores);
    final_kernel<<<1, 64, 0, stream>>>(scores, out);
}

// Round 3
// 420.666 us; speedup vs baseline: 1.3959x; 1.3959x over previous
//
#include <hip/hip_runtime.h>
#include <cmath>

#define B_      32
#define N_      4096
#define D_      512
#define D4      (D_/4)        // 128 float4 per row
#define NCH     64            // chunks per batch
#define RPC     64            // rows per chunk  (NCH*RPC == N_)
#define IN_DIM  1541          // 3*D + 5
#define NEG_SENT (-1.0e8f)
#define BIGNEG   (1.0e30f)

// ---------------- Kernel 1: per-(batch,chunk) partial sum/sumsq/max ----------
// Branch-free streaming with w in {0,1}. SINGLE accumulator set (12 VGPRs) +
// unroll-4 loads: ~45 live VGPRs, no spills (R2's 179 MB WRITE_SIZE was
// scratch spill from 12-float4-acc + 8-float4-load under a 64-VGPR cap).
__global__ __launch_bounds__(128) void stats_partial_kernel(
    const float* __restrict__ x, const float* __restrict__ mask,
    float4* __restrict__ psum, float4* __restrict__ psq,
    float4* __restrict__ pmax, float* __restrict__ pcnt)
{
    __shared__ float sw[RPC];   // 0 or 1
    __shared__ float so[RPC];   // 0 (valid) or -1e30 (invalid): (w-1)*1e30
    const int tx = threadIdx.x;    // 0..127, owns float4 lane tx
    const int c  = blockIdx.x;     // chunk
    const int b  = blockIdx.y;     // batch

    if (tx < RPC) {   // RPC==64: wave 0 handles mask + count
        const float mv = mask[b * N_ + c * RPC + tx];
        const float w  = (mv > NEG_SENT) ? 1.f : 0.f;
        sw[tx] = w;
        so[tx] = (w - 1.f) * BIGNEG;
        float cv = w;   // wave-level count reduction (64 lanes)
        #pragma unroll
        for (int off = 32; off > 0; off >>= 1) cv += __shfl_down(cv, off);
        if (tx == 0) pcnt[b * NCH + c] = cv;
    }
    __syncthreads();

    const float4* __restrict__ xb =
        (const float4*)x + ((size_t)b * N_ + (size_t)c * RPC) * D4 + tx;

    float4 s  = {0,0,0,0};
    float4 q  = {0,0,0,0};
    float4 mx = {-BIGNEG,-BIGNEG,-BIGNEG,-BIGNEG};

    #pragma unroll 4
    for (int j = 0; j < RPC; ++j) {
        const float4 v = xb[(size_t)j * D4];
        const float  w = sw[j];
        const float  o = so[j];
        const float tvx = v.x*w, tvy = v.y*w, tvz = v.z*w, tvw = v.w*w;
        s.x += tvx; s.y += tvy; s.z += tvz; s.w += tvw;
        q.x = fmaf(tvx, v.x, q.x); q.y = fmaf(tvy, v.y, q.y);
        q.z = fmaf(tvz, v.z, q.z); q.w = fmaf(tvw, v.w, q.w);
        mx.x = fmaxf(mx.x, fmaf(w, v.x, o));
        mx.y = fmaxf(mx.y, fmaf(w, v.y, o));
        mx.z = fmaxf(mx.z, fmaf(w, v.z, o));
        mx.w = fmaxf(mx.w, fmaf(w, v.w, o));
    }

    const size_t idx = ((size_t)(b * NCH + c)) * D4 + tx;
    psum[idx] = s; psq[idx] = q; pmax[idx] = mx;
}

// ---------------- Kernel 2: combine partials, build g, run MLP --------------
__global__ __launch_bounds__(256) void mlp_kernel(
    const float4* __restrict__ psum, const float4* __restrict__ psq,
    const float4* __restrict__ pmax, const float* __restrict__ pcnt,
    const float* __restrict__ W1, const float* __restrict__ b1,
    const float* __restrict__ W2, const float* __restrict__ b2,
    const float* __restrict__ W3, const float* __restrict__ b3,
    float* __restrict__ scores)
{
    __shared__ float4 Ss[2][D4], Sq[2][D4], Sm[2][D4];
    __shared__ float g[IN_DIM];
    __shared__ float h1p[4*64];
    __shared__ float h1[64];
    __shared__ float h2[32];
    __shared__ float scnt;

    const int tid = threadIdx.x;     // 0..255
    const int tx  = tid & 127;       // float4 lane
    const int ty  = tid >> 7;        // 0/1: which half of the chunks
    const int b   = blockIdx.x;

    {   // 2-way parallel chunk reduction, unrolled for load pipelining
        float4 s = {0,0,0,0}, q = {0,0,0,0};
        float4 mx = {-BIGNEG,-BIGNEG,-BIGNEG,-BIGNEG};
        const int c0 = ty * (NCH/2);
        #pragma unroll 4
        for (int c = c0; c < c0 + NCH/2; ++c) {
            const size_t idx = ((size_t)(b * NCH + c)) * D4 + tx;
            float4 a = psum[idx], u = psq[idx], w = pmax[idx];
            s.x += a.x; s.y += a.y; s.z += a.z; s.w += a.w;
            q.x += u.x; q.y += u.y; q.z += u.z; q.w += u.w;
            mx.x = fmaxf(mx.x,w.x); mx.y = fmaxf(mx.y,w.y);
            mx.z = fmaxf(mx.z,w.z); mx.w = fmaxf(mx.w,w.w);
        }
        Ss[ty][tx] = s; Sq[ty][tx] = q; Sm[ty][tx] = mx;
    }
    if (tid < 64) {   // count reduction over 64 chunks, first wave
        float cv = pcnt[b * NCH + tid];
        #pragma unroll
        for (int off = 32; off > 0; off >>= 1) cv += __shfl_down(cv, off);
        if (tid == 0) scnt = cv;
    }
    __syncthreads();

    const float cnt = scnt;
    if (ty == 0) {   // merge halves, compute g
        float4 s = Ss[0][tx], s_ = Ss[1][tx];
        float4 q = Sq[0][tx], q_ = Sq[1][tx];
        float4 mx = Sm[0][tx], m_ = Sm[1][tx];
        s.x += s_.x; s.y += s_.y; s.z += s_.z; s.w += s_.w;
        q.x += q_.x; q.y += q_.y; q.z += q_.z; q.w += q_.w;
        mx.x = fmaxf(mx.x,m_.x); mx.y = fmaxf(mx.y,m_.y);
        mx.z = fmaxf(mx.z,m_.z); mx.w = fmaxf(mx.w,m_.w);

        const bool  has = cnt > 0.f;
        const float inv = 1.f / fmaxf(cnt, 1.f);
        const float dn  = 1.f / fmaxf(cnt - 1.f, 1.f);
        float sa[4] = {s.x,s.y,s.z,s.w};
        float qa[4] = {q.x,q.y,q.z,q.w};
        float ma[4] = {mx.x,mx.y,mx.z,mx.w};
        #pragma unroll
        for (int k = 0; k < 4; ++k) {
            const int d = 4*tx + k;
            const float mn = has ? sa[k] * inv : 0.f;
            const float vv = fmaxf((qa[k] - cnt * mn * mn) * dn, 0.f);
            g[d]        = mn;
            g[D_ + d]   = has ? ma[k] : 0.f;
            g[2*D_ + d] = has ? sqrtf(vv) : 0.f;
        }
        if (tx == 0) {
            g[3*D_ + 0] = logf(cnt + 1.f) * 0.2f;
            g[3*D_ + 1] = 0.1f;
            g[3*D_ + 2] = 0.2f;
            g[3*D_ + 3] = 4.0f;
            g[3*D_ + 4] = 0.1f;
        }
    }
    __syncthreads();

    {   // layer 1: 1541 -> 64, 4-way split over input dim
        const int o   = tid & 63;
        const int grp = tid >> 6;    // 0..3
        float a = 0.f;
        #pragma unroll 4
        for (int i = grp; i < IN_DIM; i += 4)
            a = fmaf(g[i], W1[i*64 + o], a);
        h1p[tid] = a;
    }
    __syncthreads();
    if (tid < 64) {
        float a = b1[tid] + ((h1p[tid] + h1p[64+tid]) + (h1p[128+tid] + h1p[192+tid]));
        h1[tid] = fmaxf(a, 0.f);
    }
    __syncthreads();

    if (tid < 32) {   // layer 2: 64 -> 32
        float a = b2[tid];
        #pragma unroll
        for (int i = 0; i < 64; ++i) a = fmaf(h1[i], W2[i*32 + tid], a);
        h2[tid] = fmaxf(a, 0.f);
    }
    __syncthreads();

    if (tid == 0) {   // layer 3: 32 -> 1, sigmoid
        float a = b3[0];
        #pragma unroll
        for (int i = 0; i < 32; ++i) a = fmaf(h2[i], W3[i], a);
        scores[b] = 1.f / (1.f + expf(-a));
    }
}

// ---------------- Kernel 3: reduce scores -> (num_clusters, score_mean) -----
__global__ __launch_bounds__(64) void final_kernel(
    const float* __restrict__ scores, float* __restrict__ out)
{
    const int t = threadIdx.x;
    float sc = (t < B_) ? scores[t] : 0.f;
    float r  = (t < B_) ? rintf(3.f + sc * 47.f) : 0.f;  // rintf == round-half-even == jnp.round
    #pragma unroll
    for (int off = 32; off > 0; off >>= 1) {
        sc += __shfl_down(sc, off);
        r  += __shfl_down(r,  off);
    }
    if (t == 0) {
        const float mean_r = r * (1.f / 32.f);   // exact: sum of ints / 2^5
        int nc = (int)mean_r;                    // astype(int32): truncate toward zero
        nc = nc < 3 ? 3 : (nc > 50 ? 50 : nc);
        out[0] = (float)nc;
        out[1] = sc * (1.f / 32.f);
    }
}

extern "C" void kernel_launch(void* const* d_in, const int* in_sizes, int n_in,
                              void* d_out, int out_size, void* d_ws, size_t ws_size,
                              hipStream_t stream)
{
    const float* x    = (const float*)d_in[0];
    const float* mask = (const float*)d_in[1];
    const float* W1   = (const float*)d_in[2];
    const float* b1   = (const float*)d_in[3];
    const float* W2   = (const float*)d_in[4];
    const float* b2   = (const float*)d_in[5];
    const float* W3   = (const float*)d_in[6];
    const float* b3   = (const float*)d_in[7];
    float* out = (float*)d_out;

    // workspace: psum | psq | pmax (each B*NCH*D4 float4 = 4 MiB) | pcnt | scores
    const size_t PCOUNT = (size_t)B_ * NCH * D4;      // 262144 float4 per array
    float4* psum = (float4*)d_ws;
    float4* psq  = psum + PCOUNT;
    float4* pmax = psq  + PCOUNT;
    float*  pcnt = (float*)(pmax + PCOUNT);           // B_*NCH floats
    float*  scores = pcnt + (size_t)B_ * NCH;         // B_ floats

    dim3 gridA(NCH, B_);
    stats_partial_kernel<<<gridA, 128, 0, stream>>>(x, mask, psum, psq, pmax, pcnt);
    mlp_kernel<<<B_, 256, 0, stream>>>(psum, psq, pmax, pcnt,
                                       W1, b1, W2, b2, W3, b3, scores);
    final_kernel<<<1, 64, 0, stream>>>(scores, out);
}

// Round 4
// 397.128 us; speedup vs baseline: 1.4786x; 1.0593x over previous
//
#include <hip/hip_runtime.h>
#include <cmath>

#define B_      32
#define N_      4096
#define D_      512
#define D4      (D_/4)        // 128 float4 per row
#define NCH     64            // chunks per batch
#define RPC     64            // rows per chunk  (NCH*RPC == N_)
#define IN_DIM  1541          // 3*D + 5
#define GSTRIDE 1568          // padded g row stride
#define NSPLIT  8             // layer-1 input-dim splits
#define CHUNK   193           // ceil(1541/8)
#define NEG_SENT (-1.0e8f)
#define BIGNEG   (1.0e30f)

// ---------------- Kernel 1: per-(batch,chunk) partial sum/sumsq/max ----------
// Branch-free streaming, single accumulator set (no spills), unroll-4 loads.
// At BW roof (~40 us for 256 MiB) — unchanged from R3.
__global__ __launch_bounds__(128) void stats_partial_kernel(
    const float* __restrict__ x, const float* __restrict__ mask,
    float4* __restrict__ psum, float4* __restrict__ psq,
    float4* __restrict__ pmax, float* __restrict__ pcnt)
{
    __shared__ float sw[RPC];   // 0 or 1
    __shared__ float so[RPC];   // 0 (valid) or -1e30 (invalid): (w-1)*1e30
    const int tx = threadIdx.x;    // 0..127, owns float4 lane tx
    const int c  = blockIdx.x;     // chunk
    const int b  = blockIdx.y;     // batch

    if (tx < RPC) {   // RPC==64: wave 0 handles mask + count
        const float mv = mask[b * N_ + c * RPC + tx];
        const float w  = (mv > NEG_SENT) ? 1.f : 0.f;
        sw[tx] = w;
        so[tx] = (w - 1.f) * BIGNEG;
        float cv = w;
        #pragma unroll
        for (int off = 32; off > 0; off >>= 1) cv += __shfl_down(cv, off);
        if (tx == 0) pcnt[b * NCH + c] = cv;
    }
    __syncthreads();

    const float4* __restrict__ xb =
        (const float4*)x + ((size_t)b * N_ + (size_t)c * RPC) * D4 + tx;

    float4 s  = {0,0,0,0};
    float4 q  = {0,0,0,0};
    float4 mx = {-BIGNEG,-BIGNEG,-BIGNEG,-BIGNEG};

    #pragma unroll 4
    for (int j = 0; j < RPC; ++j) {
        const float4 v = xb[(size_t)j * D4];
        const float  w = sw[j];
        const float  o = so[j];
        const float tvx = v.x*w, tvy = v.y*w, tvz = v.z*w, tvw = v.w*w;
        s.x += tvx; s.y += tvy; s.z += tvz; s.w += tvw;
        q.x = fmaf(tvx, v.x, q.x); q.y = fmaf(tvy, v.y, q.y);
        q.z = fmaf(tvz, v.z, q.z); q.w = fmaf(tvw, v.w, q.w);
        mx.x = fmaxf(mx.x, fmaf(w, v.x, o));
        mx.y = fmaxf(mx.y, fmaf(w, v.y, o));
        mx.z = fmaxf(mx.z, fmaf(w, v.z, o));
        mx.w = fmaxf(mx.w, fmaf(w, v.w, o));
    }

    const size_t idx = ((size_t)(b * NCH + c)) * D4 + tx;
    psum[idx] = s; psq[idx] = q; pmax[idx] = mx;
}

// ---------------- Kernel 2: combine partials -> g (global) ------------------
__global__ __launch_bounds__(256) void combine_g_kernel(
    const float4* __restrict__ psum, const float4* __restrict__ psq,
    const float4* __restrict__ pmax, const float* __restrict__ pcnt,
    float* __restrict__ g_all)
{
    __shared__ float4 Ss[2][D4], Sq[2][D4], Sm[2][D4];
    __shared__ float scnt;

    const int tid = threadIdx.x;     // 0..255
    const int tx  = tid & 127;       // float4 lane
    const int ty  = tid >> 7;        // 0/1: which half of the chunks
    const int b   = blockIdx.x;

    {   // 2-way parallel chunk reduction
        float4 s = {0,0,0,0}, q = {0,0,0,0};
        float4 mx = {-BIGNEG,-BIGNEG,-BIGNEG,-BIGNEG};
        const int c0 = ty * (NCH/2);
        #pragma unroll 4
        for (int c = c0; c < c0 + NCH/2; ++c) {
            const size_t idx = ((size_t)(b * NCH + c)) * D4 + tx;
            float4 a = psum[idx], u = psq[idx], w = pmax[idx];
            s.x += a.x; s.y += a.y; s.z += a.z; s.w += a.w;
            q.x += u.x; q.y += u.y; q.z += u.z; q.w += u.w;
            mx.x = fmaxf(mx.x,w.x); mx.y = fmaxf(mx.y,w.y);
            mx.z = fmaxf(mx.z,w.z); mx.w = fmaxf(mx.w,w.w);
        }
        Ss[ty][tx] = s; Sq[ty][tx] = q; Sm[ty][tx] = mx;
    }
    if (tid < 64) {   // count reduction over 64 chunks
        float cv = pcnt[b * NCH + tid];
        #pragma unroll
        for (int off = 32; off > 0; off >>= 1) cv += __shfl_down(cv, off);
        if (tid == 0) scnt = cv;
    }
    __syncthreads();

    const float cnt = scnt;
    float* __restrict__ g = g_all + (size_t)b * GSTRIDE;
    if (ty == 0) {   // merge halves, compute g
        float4 s = Ss[0][tx], s_ = Ss[1][tx];
        float4 q = Sq[0][tx], q_ = Sq[1][tx];
        float4 mx = Sm[0][tx], m_ = Sm[1][tx];
        s.x += s_.x; s.y += s_.y; s.z += s_.z; s.w += s_.w;
        q.x += q_.x; q.y += q_.y; q.z += q_.z; q.w += q_.w;
        mx.x = fmaxf(mx.x,m_.x); mx.y = fmaxf(mx.y,m_.y);
        mx.z = fmaxf(mx.z,m_.z); mx.w = fmaxf(mx.w,m_.w);

        const bool  has = cnt > 0.f;
        const float inv = 1.f / fmaxf(cnt, 1.f);
        const float dn  = 1.f / fmaxf(cnt - 1.f, 1.f);
        float sa[4] = {s.x,s.y,s.z,s.w};
        float qa[4] = {q.x,q.y,q.z,q.w};
        float ma[4] = {mx.x,mx.y,mx.z,mx.w};
        #pragma unroll
        for (int k = 0; k < 4; ++k) {
            const int d = 4*tx + k;
            const float mn = has ? sa[k] * inv : 0.f;
            const float vv = fmaxf((qa[k] - cnt * mn * mn) * dn, 0.f);
            g[d]        = mn;
            g[D_ + d]   = has ? ma[k] : 0.f;
            g[2*D_ + d] = has ? sqrtf(vv) : 0.f;
        }
        if (tx == 0) {
            g[3*D_ + 0] = logf(cnt + 1.f) * 0.2f;
            g[3*D_ + 1] = 0.1f;
            g[3*D_ + 2] = 0.2f;
            g[3*D_ + 3] = 4.0f;
            g[3*D_ + 4] = 0.1f;
        }
    }
}

// ---------------- Kernel 3: layer-1 partial dot products --------------------
// 8 i-chunks x 32 batches = 256 blocks (1/CU) x 64 threads: deep, parallel
// W1 streaming instead of R3's 32-block latency-serial layer 1.
__global__ __launch_bounds__(64) void layer1_kernel(
    const float* __restrict__ g_all, const float* __restrict__ W1,
    float* __restrict__ h1p)
{
    __shared__ float sg[CHUNK];
    const int o  = threadIdx.x;          // 0..63 output unit
    const int c  = blockIdx.x;           // 0..7 input chunk
    const int b  = blockIdx.y;           // batch
    const int i0 = c * CHUNK;
    const int len = (IN_DIM - i0) < CHUNK ? (IN_DIM - i0) : CHUNK;

    for (int j = o; j < len; j += 64) sg[j] = g_all[(size_t)b * GSTRIDE + i0 + j];
    __syncthreads();

    const float* __restrict__ Wp = W1 + (size_t)i0 * 64 + o;
    float a = 0.f;
    #pragma unroll 8
    for (int k = 0; k < len; ++k)
        a = fmaf(sg[k], Wp[(size_t)k * 64], a);
    h1p[((size_t)b * NSPLIT + c) * 64 + o] = a;
}

// ---------------- Kernel 4: finish — reduce partials, L2, L3, output --------
__global__ __launch_bounds__(1024) void finish_kernel(
    const float* __restrict__ h1p, const float* __restrict__ b1,
    const float* __restrict__ W2, const float* __restrict__ b2,
    const float* __restrict__ W3, const float* __restrict__ b3,
    float* __restrict__ out)
{
    __shared__ float h1s[B_ * 64];    // 8 KB
    __shared__ float h2s[B_ * 33];    // padded stride 33: no bank conflicts
    const int tid = threadIdx.x;      // 0..1023

    #pragma unroll
    for (int r = 0; r < 2; ++r) {     // layer-1 reduce+bias+relu: 2048 outputs
        const int oi = tid + r * 1024;   // b*64+o
        const int b = oi >> 6, o = oi & 63;
        float a = b1[o];
        #pragma unroll
        for (int c = 0; c < NSPLIT; ++c) a += h1p[((size_t)b * NSPLIT + c) * 64 + o];
        h1s[oi] = fmaxf(a, 0.f);
    }
    __syncthreads();

    {   // layer 2: 32 batches x 32 outputs, one thread each
        const int b = tid >> 5, o = tid & 31;
        float a = b2[o];
        #pragma unroll
        for (int i = 0; i < 64; ++i) a = fmaf(h1s[b*64 + i], W2[i*32 + o], a);
        h2s[b*33 + o] = fmaxf(a, 0.f);
    }
    __syncthreads();

    if (tid < 32) {   // layer 3 + sigmoid + final reduction (all in wave 0)
        const int b = tid;
        float a = b3[0];
        #pragma unroll
        for (int i = 0; i < 32; ++i) a = fmaf(h2s[b*33 + i], W3[i], a);
        float sc = 1.f / (1.f + expf(-a));
        float r  = rintf(3.f + sc * 47.f);   // rintf == round-half-even == jnp.round
        #pragma unroll
        for (int off = 16; off > 0; off >>= 1) {
            sc += __shfl_down(sc, off);
            r  += __shfl_down(r,  off);
        }
        if (tid == 0) {
            const float mean_r = r * (1.f / 32.f);   // exact: sum of ints / 2^5
            int nc = (int)mean_r;                    // astype(int32): trunc toward 0
            nc = nc < 3 ? 3 : (nc > 50 ? 50 : nc);
            out[0] = (float)nc;
            out[1] = sc * (1.f / 32.f);
        }
    }
}

extern "C" void kernel_launch(void* const* d_in, const int* in_sizes, int n_in,
                              void* d_out, int out_size, void* d_ws, size_t ws_size,
                              hipStream_t stream)
{
    const float* x    = (const float*)d_in[0];
    const float* mask = (const float*)d_in[1];
    const float* W1   = (const float*)d_in[2];
    const float* b1   = (const float*)d_in[3];
    const float* W2   = (const float*)d_in[4];
    const float* b2   = (const float*)d_in[5];
    const float* W3   = (const float*)d_in[6];
    const float* b3   = (const float*)d_in[7];
    float* out = (float*)d_out;

    // ws: psum|psq|pmax (4 MiB each) | pcnt | g_all (200 KB) | h1p (64 KB)
    const size_t PCOUNT = (size_t)B_ * NCH * D4;      // 262144 float4 per array
    float4* psum = (float4*)d_ws;
    float4* psq  = psum + PCOUNT;
    float4* pmax = psq  + PCOUNT;
    float*  pcnt = (float*)(pmax + PCOUNT);           // B_*NCH floats
    float*  g_all = pcnt + (size_t)B_ * NCH;          // B_*GSTRIDE floats
    float*  h1p   = g_all + (size_t)B_ * GSTRIDE;     // B_*NSPLIT*64 floats

    dim3 gridA(NCH, B_);
    stats_partial_kernel<<<gridA, 128, 0, stream>>>(x, mask, psum, psq, pmax, pcnt);
    combine_g_kernel<<<B_, 256, 0, stream>>>(psum, psq, pmax, pcnt, g_all);
    dim3 gridL1(NSPLIT, B_);
    layer1_kernel<<<gridL1, 64, 0, stream>>>(g_all, W1, h1p);
    finish_kernel<<<1, 1024, 0, stream>>>(h1p, b1, W2, b2, W3, b3, out);
}

// Round 5
// 380.888 us; speedup vs baseline: 1.5416x; 1.0426x over previous
//
#include <hip/hip_runtime.h>
#include <cmath>

#define B_      32
#define N_      4096
#define D_      512
#define D4      (D_/4)        // 128 float4 per row
#define NCH     32            // chunks per batch
#define RPC     128           // rows per chunk  (NCH*RPC == N_)
#define IN_DIM  1541          // 3*D + 5
#define GSTRIDE 1568          // padded g row stride
#define NSPLIT  8             // layer-1 input-dim splits
#define CHUNK   193           // ceil(1541/8)
#define NEG_SENT (-1.0e8f)
#define BIGNEG   (1.0e30f)

// ---------------- Kernel 1: per-(batch,chunk) partial sum/sumsq/max ----------
// Valid-row skip: ballot-compacted row indices (stable order => bit-identical
// sums vs streaming-with-zero-weight), ~25% fewer HBM bytes. 1024 blocks x
// 128 thr, 16 waves/CU hide the ds_read->global_load index chain.
__global__ __launch_bounds__(128) void stats_partial_kernel(
    const float* __restrict__ x, const float* __restrict__ mask,
    float4* __restrict__ psum, float4* __restrict__ psq,
    float4* __restrict__ pmax, float* __restrict__ pcnt)
{
    __shared__ int sidx[RPC];
    __shared__ int swc0, swc1;
    const int tx   = threadIdx.x;   // 0..127: float4 lane AND row slot
    const int wave = tx >> 6;
    const int lane = tx & 63;
    const int c    = blockIdx.x;    // chunk
    const int b    = blockIdx.y;    // batch

    {   // stable ballot compaction of valid rows
        const float mv = mask[b * N_ + c * RPC + tx];
        const bool pred = mv > NEG_SENT;
        const unsigned long long bal = __ballot(pred);
        const int prefix = __popcll(bal & ((1ull << lane) - 1ull));
        if (lane == 0) { if (wave == 0) swc0 = __popcll(bal); else swc1 = __popcll(bal); }
        __syncthreads();
        const int base = (wave == 0) ? 0 : swc0;
        if (pred) sidx[base + prefix] = tx;
    }
    __syncthreads();
    const int m = swc0 + swc1;
    if (tx == 0) pcnt[b * NCH + c] = (float)m;

    const float4* __restrict__ xb =
        (const float4*)x + ((size_t)b * N_ + (size_t)c * RPC) * D4 + tx;

    float4 s  = {0,0,0,0};
    float4 q  = {0,0,0,0};
    float4 mx = {-BIGNEG,-BIGNEG,-BIGNEG,-BIGNEG};

    #pragma unroll 4
    for (int i = 0; i < m; ++i) {
        const int r = sidx[i];
        const float4 v = xb[(size_t)r * D4];
        s.x += v.x; s.y += v.y; s.z += v.z; s.w += v.w;
        q.x = fmaf(v.x, v.x, q.x); q.y = fmaf(v.y, v.y, q.y);
        q.z = fmaf(v.z, v.z, q.z); q.w = fmaf(v.w, v.w, q.w);
        mx.x = fmaxf(mx.x, v.x); mx.y = fmaxf(mx.y, v.y);
        mx.z = fmaxf(mx.z, v.z); mx.w = fmaxf(mx.w, v.w);
    }

    const size_t idx = ((size_t)(b * NCH + c)) * D4 + tx;
    psum[idx] = s; psq[idx] = q; pmax[idx] = mx;
}

// ---------------- Kernel 2: combine partials -> g (global) ------------------
__global__ __launch_bounds__(256) void combine_g_kernel(
    const float4* __restrict__ psum, const float4* __restrict__ psq,
    const float4* __restrict__ pmax, const float* __restrict__ pcnt,
    float* __restrict__ g_all)
{
    __shared__ float4 Ss[2][D4], Sq[2][D4], Sm[2][D4];
    __shared__ float scnt;

    const int tid = threadIdx.x;     // 0..255
    const int tx  = tid & 127;       // float4 lane
    const int ty  = tid >> 7;        // 0/1: which half of the chunks
    const int b   = blockIdx.x;

    {   // 2-way parallel chunk reduction
        float4 s = {0,0,0,0}, q = {0,0,0,0};
        float4 mx = {-BIGNEG,-BIGNEG,-BIGNEG,-BIGNEG};
        const int c0 = ty * (NCH/2);
        #pragma unroll 4
        for (int c = c0; c < c0 + NCH/2; ++c) {
            const size_t idx = ((size_t)(b * NCH + c)) * D4 + tx;
            float4 a = psum[idx], u = psq[idx], w = pmax[idx];
            s.x += a.x; s.y += a.y; s.z += a.z; s.w += a.w;
            q.x += u.x; q.y += u.y; q.z += u.z; q.w += u.w;
            mx.x = fmaxf(mx.x,w.x); mx.y = fmaxf(mx.y,w.y);
            mx.z = fmaxf(mx.z,w.z); mx.w = fmaxf(mx.w,w.w);
        }
        Ss[ty][tx] = s; Sq[ty][tx] = q; Sm[ty][tx] = mx;
    }
    if (tid < NCH) {   // count reduction over 32 chunks (wave 0)
        float cv = pcnt[b * NCH + tid];
        #pragma unroll
        for (int off = 16; off > 0; off >>= 1) cv += __shfl_down(cv, off);
        if (tid == 0) scnt = cv;
    }
    __syncthreads();

    const float cnt = scnt;
    float* __restrict__ g = g_all + (size_t)b * GSTRIDE;
    if (ty == 0) {   // merge halves, compute g
        float4 s = Ss[0][tx], s_ = Ss[1][tx];
        float4 q = Sq[0][tx], q_ = Sq[1][tx];
        float4 mx = Sm[0][tx], m_ = Sm[1][tx];
        s.x += s_.x; s.y += s_.y; s.z += s_.z; s.w += s_.w;
        q.x += q_.x; q.y += q_.y; q.z += q_.z; q.w += q_.w;
        mx.x = fmaxf(mx.x,m_.x); mx.y = fmaxf(mx.y,m_.y);
        mx.z = fmaxf(mx.z,m_.z); mx.w = fmaxf(mx.w,m_.w);

        const bool  has = cnt > 0.f;
        const float inv = 1.f / fmaxf(cnt, 1.f);
        const float dn  = 1.f / fmaxf(cnt - 1.f, 1.f);
        float sa[4] = {s.x,s.y,s.z,s.w};
        float qa[4] = {q.x,q.y,q.z,q.w};
        float ma[4] = {mx.x,mx.y,mx.z,mx.w};
        #pragma unroll
        for (int k = 0; k < 4; ++k) {
            const int d = 4*tx + k;
            const float mn = has ? sa[k] * inv : 0.f;
            const float vv = fmaxf((qa[k] - cnt * mn * mn) * dn, 0.f);
            g[d]        = mn;
            g[D_ + d]   = has ? ma[k] : 0.f;
            g[2*D_ + d] = has ? sqrtf(vv) : 0.f;
        }
        if (tx == 0) {
            g[3*D_ + 0] = logf(cnt + 1.f) * 0.2f;
            g[3*D_ + 1] = 0.1f;
            g[3*D_ + 2] = 0.2f;
            g[3*D_ + 3] = 4.0f;
            g[3*D_ + 4] = 0.1f;
        }
    }
}

// ---------------- Kernel 3: layer-1 partial dot products --------------------
// 8 i-chunks x 32 batches = 256 blocks x 64 threads.
__global__ __launch_bounds__(64) void layer1_kernel(
    const float* __restrict__ g_all, const float* __restrict__ W1,
    float* __restrict__ h1p)
{
    __shared__ float sg[CHUNK];
    const int o  = threadIdx.x;          // 0..63 output unit
    const int c  = blockIdx.x;           // 0..7 input chunk
    const int b  = blockIdx.y;           // batch
    const int i0 = c * CHUNK;
    const int len = (IN_DIM - i0) < CHUNK ? (IN_DIM - i0) : CHUNK;

    for (int j = o; j < len; j += 64) sg[j] = g_all[(size_t)b * GSTRIDE + i0 + j];
    __syncthreads();

    const float* __restrict__ Wp = W1 + (size_t)i0 * 64 + o;
    float a = 0.f;
    #pragma unroll 8
    for (int k = 0; k < len; ++k)
        a = fmaf(sg[k], Wp[(size_t)k * 64], a);
    h1p[((size_t)b * NSPLIT + c) * 64 + o] = a;
}

// ---------------- Kernel 4: finish — reduce partials, L2, L3, output --------
__global__ __launch_bounds__(1024) void finish_kernel(
    const float* __restrict__ h1p, const float* __restrict__ b1,
    const float* __restrict__ W2, const float* __restrict__ b2,
    const float* __restrict__ W3, const float* __restrict__ b3,
    float* __restrict__ out)
{
    __shared__ float h1s[B_ * 64];    // 8 KB
    __shared__ float h2s[B_ * 33];    // padded stride 33: no bank conflicts
    const int tid = threadIdx.x;      // 0..1023

    #pragma unroll
    for (int r = 0; r < 2; ++r) {     // layer-1 reduce+bias+relu: 2048 outputs
        const int oi = tid + r * 1024;   // b*64+o
        const int b = oi >> 6, o = oi & 63;
        float a = b1[o];
        #pragma unroll
        for (int c = 0; c < NSPLIT; ++c) a += h1p[((size_t)b * NSPLIT + c) * 64 + o];
        h1s[oi] = fmaxf(a, 0.f);
    }
    __syncthreads();

    {   // layer 2: 32 batches x 32 outputs, one thread each
        const int b = tid >> 5, o = tid & 31;
        float a = b2[o];
        #pragma unroll
        for (int i = 0; i < 64; ++i) a = fmaf(h1s[b*64 + i], W2[i*32 + o], a);
        h2s[b*33 + o] = fmaxf(a, 0.f);
    }
    __syncthreads();

    if (tid < 32) {   // layer 3 + sigmoid + final reduction (all in wave 0)
        const int b = tid;
        float a = b3[0];
        #pragma unroll
        for (int i = 0; i < 32; ++i) a = fmaf(h2s[b*33 + i], W3[i], a);
        float sc = 1.f / (1.f + expf(-a));
        float r  = rintf(3.f + sc * 47.f);   // rintf == round-half-even == jnp.round
        #pragma unroll
        for (int off = 16; off > 0; off >>= 1) {
            sc += __shfl_down(sc, off);
            r  += __shfl_down(r,  off);
        }
        if (tid == 0) {
            const float mean_r = r * (1.f / 32.f);   // exact: sum of ints / 2^5
            int nc = (int)mean_r;                    // astype(int32): trunc toward 0
            nc = nc < 3 ? 3 : (nc > 50 ? 50 : nc);
            out[0] = (float)nc;
            out[1] = sc * (1.f / 32.f);
        }
    }
}

extern "C" void kernel_launch(void* const* d_in, const int* in_sizes, int n_in,
                              void* d_out, int out_size, void* d_ws, size_t ws_size,
                              hipStream_t stream)
{
    const float* x    = (const float*)d_in[0];
    const float* mask = (const float*)d_in[1];
    const float* W1   = (const float*)d_in[2];
    const float* b1   = (const float*)d_in[3];
    const float* W2   = (const float*)d_in[4];
    const float* b2   = (const float*)d_in[5];
    const float* W3   = (const float*)d_in[6];
    const float* b3   = (const float*)d_in[7];
    float* out = (float*)d_out;

    // ws: psum|psq|pmax (2 MiB each) | pcnt | g_all (200 KB) | h1p (64 KB)
    const size_t PCOUNT = (size_t)B_ * NCH * D4;      // 131072 float4 per array
    float4* psum = (float4*)d_ws;
    float4* psq  = psum + PCOUNT;
    float4* pmax = psq  + PCOUNT;
    float*  pcnt = (float*)(pmax + PCOUNT);           // B_*NCH floats
    float*  g_all = pcnt + (size_t)B_ * NCH;          // B_*GSTRIDE floats
    float*  h1p   = g_all + (size_t)B_ * GSTRIDE;     // B_*NSPLIT*64 floats

    dim3 gridA(NCH, B_);
    stats_partial_kernel<<<gridA, 128, 0, stream>>>(x, mask, psum, psq, pmax, pcnt);
    combine_g_kernel<<<B_, 256, 0, stream>>>(psum, psq, pmax, pcnt, g_all);
    dim3 gridL1(NSPLIT, B_);
    layer1_kernel<<<gridL1, 64, 0, stream>>>(g_all, W1, h1p);
    finish_kernel<<<1, 1024, 0, stream>>>(h1p, b1, W2, b2, W3, b3, out);
}